// Round 1
// baseline (264.969 us; speedup 1.0000x reference)
//
#include <hip/hip_runtime.h>
#include <hip/hip_bf16.h>

#define N_ 16
#define D_ 2048
#define H_ 32
#define W_ 32
#define HW_ 1024
#define F_ 512

typedef unsigned short u16;
typedef unsigned int u32;
typedef __attribute__((ext_vector_type(8))) short bf16x8;
typedef __attribute__((ext_vector_type(4))) float f32x4;

__device__ __forceinline__ u16 f2bf(float f) {
  union { float fv; u32 u; } c; c.fv = f;
  u32 u = c.u;
  u32 r = (u + 0x7fffu + ((u >> 16) & 1u)) >> 16;   // RNE
  return (u16)r;
}
__device__ __forceinline__ float bflo(u32 u) { union { u32 u; float f; } c; c.u = u << 16; return c.f; }
__device__ __forceinline__ float bfhi(u32 u) { union { u32 u; float f; } c; c.u = u & 0xffff0000u; return c.f; }

#define GLD_LDS16(gp, lp) __builtin_amdgcn_global_load_lds( \
    (const __attribute__((address_space(1))) void*)(gp), \
    (__attribute__((address_space(3))) void*)(lp), 16, 0, 0)

// ---- K1: sum of squares over channel dim -> sumsq[n][hw] (atomic partials) ----
__global__ __launch_bounds__(256) void k_sumsq(const float* __restrict__ x, float* __restrict__ sumsq) {
  const int n = blockIdx.x;        // 16
  const int dc = blockIdx.y;       // 32 chunks x 64 d
  const int t = threadIdx.x;
  const float* xp = x + ((size_t)n * D_ + (size_t)dc * 64) * HW_;
  float s0 = 0.f, s1 = 0.f, s2 = 0.f, s3 = 0.f;
  for (int d = 0; d < 64; ++d) {
    const float* row = xp + (size_t)d * HW_;
    float v0 = row[t], v1 = row[t + 256], v2 = row[t + 512], v3 = row[t + 768];
    s0 += v0 * v0; s1 += v1 * v1; s2 += v2 * v2; s3 += v3 * v3;
  }
  atomicAdd(&sumsq[n * HW_ + t      ], s0);
  atomicAdd(&sumsq[n * HW_ + t + 256], s1);
  atomicAdd(&sumsq[n * HW_ + t + 512], s2);
  atomicAdd(&sumsq[n * HW_ + t + 768], s3);
}

// ---- K2: normalize, 3x3 truncated box sum -> boxT[n*HW+hw][d] (bf16), GeM partials ----
__global__ __launch_bounds__(256) void k_box(const float* __restrict__ x,
    const float* __restrict__ sumsq, const float* __restrict__ pvec,
    float* __restrict__ gbuf, u16* __restrict__ boxT) {
  const int n = blockIdx.x, dt = blockIdx.y, ht = blockIdx.z;
  const int d0 = dt * 128, h0 = ht * 4;
  const int t = threadIdx.x;
  __shared__ __align__(16) u16 xs[192 * 132];   // [hw' 6x32][d 128 pad->132], bf16 of normalized x
  __shared__ float rn[192];
  const float p = pvec[0];

  if (t < 192) {
    int hp = h0 - 1 + (t >> 5);
    float r = 0.f;
    if (hp >= 0 && hp < H_) r = 1.0f / fmaxf(sqrtf(sumsq[n * HW_ + hp * W_ + (t & 31)]), 1e-12f);
    rn[t] = r;
  }
  __syncthreads();

  const size_t xbase = ((size_t)n * D_ + d0) * HW_;
  for (int i = t; i < 128 * 192; i += 256) {
    int d = i / 192;
    int hwp = i - d * 192;
    int hp = h0 - 1 + (hwp >> 5);
    float v = 0.f;
    if (hp >= 0 && hp < H_) v = x[xbase + (size_t)d * HW_ + hp * W_ + (hwp & 31)] * rn[hwp];
    xs[hwp * 132 + d] = f2bf(v);
  }
  __syncthreads();

  // GeM partial: 2 threads per d, owned rows hwp in [32,160)
  {
    const int d = t >> 1, half = t & 1;
    const bool p3 = (p == 3.0f);
    float s = 0.f;
    for (int k = 0; k < 64; ++k) {
      int hwp = 32 + half * 64 + k;
      union { u32 uu; float f; } c; c.uu = (u32)xs[hwp * 132 + d] << 16;
      float cv = fmaxf(c.f, 1e-6f);
      s += p3 ? cv * cv * cv : powf(cv, p);
    }
    s += __shfl_xor(s, 1);
    if (!half) atomicAdd(&gbuf[n * D_ + d0 + d], s);
  }

  // box pass: wave wv owns local h row wv; lane dl owns d-pair 2*dl
  const int dl = t & 63, wv = t >> 6;
  const u32* xsu = (const u32*)xs;
  u32* boxu = (u32*)boxT;
  const size_t obase = ((size_t)(n * HW_ + (h0 + wv) * W_)) * (D_ / 2) + (d0 >> 1) + dl;
  for (int wc = 0; wc < 32; ++wc) {
    int hc = (wv + 1) * 32 + wc;
    float s0 = 0.f, s1 = 0.f;
    #pragma unroll
    for (int dy = -1; dy <= 1; ++dy) {
      int rb = (hc + dy * 32) * 66 + dl;
      #pragma unroll
      for (int dx = -1; dx <= 1; ++dx) {
        int w2 = wc + dx;
        if (w2 >= 0 && w2 < W_) {
          u32 u = xsu[rb + dx * 66];
          s0 += bflo(u); s1 += bfhi(u);
        }
      }
    }
    u32 o = (u32)f2bf(s0) | ((u32)f2bf(s1) << 16);
    boxu[obase + (size_t)wc * (D_ / 2)] = o;
  }
}

// ---- K3: proj_w fp32 -> bf16 ----
__global__ __launch_bounds__(256) void k_wconv(const float* __restrict__ w, u16* __restrict__ wb) {
  int i = blockIdx.x * 256 + threadIdx.x;      // 262144 threads, 4 elems each
  float4 v = ((const float4*)w)[i];
  u16 r[4] = { f2bf(v.x), f2bf(v.y), f2bf(v.z), f2bf(v.w) };
  *(uint2*)(wb + (size_t)i * 4) = *(const uint2*)r;
}

// ---- K4: GEMM [64 hw] x [512 f] x [K 2048] + bias + l2norm over f + transposed store ----
__global__ __launch_bounds__(512) void k_gemm(const u16* __restrict__ boxT,
    const u16* __restrict__ wb, const float* __restrict__ bias,
    float* __restrict__ outL) {
  const int n  = blockIdx.x >> 4;
  const int mt = blockIdx.x & 15;
  const int m0 = n * HW_ + mt * 64;
  const int hw0 = mt * 64;
  const int t = threadIdx.x;
  const int lane = t & 63, wv = t >> 6;

  __shared__ __align__(16) u16 smem[64 * 32 + 512 * 32];  // sA | sB (linear, for global_load_lds)
  u16* sA = smem;
  u16* sB = smem + 64 * 32;
  __shared__ float s_sq[8][64];
  __shared__ float s_rn[64];

  f32x4 acc[4][4];
  #pragma unroll
  for (int a = 0; a < 4; ++a)
    #pragma unroll
    for (int b = 0; b < 4; ++b) acc[a][b] = (f32x4){0.f, 0.f, 0.f, 0.f};

  const int lrow4 = lane >> 2;        // 0..15
  const int lk8   = (lane & 3) * 8;   // 0,8,16,24

  for (int kt = 0; kt < D_ / 32; ++kt) {
    const int k0 = kt * 32;
    #pragma unroll
    for (int q = 0; q < 4; ++q) {        // B tile: 512x32 bf16 = 32 chunks of 1KB
      int c = wv * 4 + q;
      int frow = c * 16 + lrow4;
      GLD_LDS16(wb + (size_t)frow * D_ + k0 + lk8, (char*)sB + (size_t)c * 1024);
    }
    if (wv < 4) {                        // A tile: 64x32 bf16 = 4 chunks
      int r = wv * 16 + lrow4;
      GLD_LDS16(boxT + (size_t)(m0 + r) * D_ + k0 + lk8, (char*)sA + (size_t)wv * 1024);
    }
    __syncthreads();
    bf16x8 af[4], bfv[4];
    #pragma unroll
    for (int mf = 0; mf < 4; ++mf)
      af[mf] = *(const bf16x8*)(sA + (mf * 16 + (lane & 15)) * 32 + (lane >> 4) * 8);
    #pragma unroll
    for (int nf = 0; nf < 4; ++nf)
      bfv[nf] = *(const bf16x8*)(sB + (wv * 64 + nf * 16 + (lane & 15)) * 32 + (lane >> 4) * 8);
    #pragma unroll
    for (int mf = 0; mf < 4; ++mf)
      #pragma unroll
      for (int nf = 0; nf < 4; ++nf)
        acc[mf][nf] = __builtin_amdgcn_mfma_f32_16x16x32_bf16(af[mf], bfv[nf], acc[mf][nf], 0, 0, 0);
    __syncthreads();
  }

  // epilogue: bias, per-row (hw) l2 norm over all 512 f, transposed store
  float badd[4];
  #pragma unroll
  for (int nf = 0; nf < 4; ++nf) badd[nf] = bias[wv * 64 + nf * 16 + (lane & 15)];
  #pragma unroll
  for (int mf = 0; mf < 4; ++mf)
    #pragma unroll
    for (int nf = 0; nf < 4; ++nf)
      #pragma unroll
      for (int j = 0; j < 4; ++j) acc[mf][nf][j] += badd[nf];

  #pragma unroll
  for (int mf = 0; mf < 4; ++mf)
    #pragma unroll
    for (int j = 0; j < 4; ++j) {
      float s = 0.f;
      #pragma unroll
      for (int nf = 0; nf < 4; ++nf) { float v = acc[mf][nf][j]; s += v * v; }
      s += __shfl_xor(s, 1); s += __shfl_xor(s, 2); s += __shfl_xor(s, 4); s += __shfl_xor(s, 8);
      if ((lane & 15) == 0) s_sq[wv][mf * 16 + (lane >> 4) * 4 + j] = s;
    }
  __syncthreads();
  if (t < 64) {
    float s = 0.f;
    #pragma unroll
    for (int w8 = 0; w8 < 8; ++w8) s += s_sq[w8][t];
    s_rn[t] = 1.0f / fmaxf(sqrtf(s), 1e-12f);
  }
  __syncthreads();

  float* ct = (float*)smem;   // reuse staging LDS: [128 f-rows][68] fp32
  for (int nf = 0; nf < 4; ++nf) {
    const int fi = wv * 16 + (lane & 15);
    #pragma unroll
    for (int mf = 0; mf < 4; ++mf)
      #pragma unroll
      for (int j = 0; j < 4; ++j) {
        int m = mf * 16 + (lane >> 4) * 4 + j;
        ct[fi * 68 + m] = acc[mf][nf][j] * s_rn[m];
      }
    __syncthreads();
    {
      int fr = t >> 2, mq = t & 3;
      int f = (fr >> 4) * 64 + nf * 16 + (fr & 15);
      float* dst = outL + ((size_t)(n * F_ + f)) * HW_ + hw0 + mq * 16;
      const float* srcp = ct + fr * 68 + mq * 16;
      float4 a0 = *(const float4*)(srcp);
      float4 a1 = *(const float4*)(srcp + 4);
      float4 a2 = *(const float4*)(srcp + 8);
      float4 a3 = *(const float4*)(srcp + 12);
      *(float4*)(dst) = a0; *(float4*)(dst + 4) = a1;
      *(float4*)(dst + 8) = a2; *(float4*)(dst + 12) = a3;
    }
    __syncthreads();
  }
}

// ---- K5: GeM finalize: gg = (gbuf/1024)^(1/p) ----
__global__ __launch_bounds__(256) void k_gem_fin(const float* __restrict__ gbuf,
    const float* __restrict__ pvec, float* __restrict__ gg) {
  int i = blockIdx.x * 256 + threadIdx.x;   // 32768
  float p = pvec[0];
  float m = gbuf[i] * (1.0f / 1024.0f);
  gg[i] = (p == 3.0f) ? cbrtf(m) : powf(m, 1.0f / p);
}

// ---- K6: gproj[n][f] = dot(gg[n], W[f]) + b[f] ----
__global__ __launch_bounds__(256) void k_gproj(const float* __restrict__ w,
    const float* __restrict__ bias, const float* __restrict__ gg,
    float* __restrict__ gproj) {
  const int f = blockIdx.x;     // 512
  const int t = threadIdx.x;
  float wreg[8];
  #pragma unroll
  for (int j = 0; j < 8; ++j) wreg[j] = w[(size_t)f * D_ + t + j * 256];
  __shared__ float red[4];
  const int lane = t & 63, wv = t >> 6;
  for (int n = 0; n < N_; ++n) {
    float s = 0.f;
    #pragma unroll
    for (int j = 0; j < 8; ++j) s += wreg[j] * gg[n * D_ + t + j * 256];
    #pragma unroll
    for (int off = 32; off >= 1; off >>= 1) s += __shfl_down(s, off);
    if (lane == 0) red[wv] = s;
    __syncthreads();
    if (t == 0) gproj[n * F_ + f] = red[0] + red[1] + red[2] + red[3] + bias[f];
    __syncthreads();
  }
}

// ---- K7: l2norm g rows -> d_out[0:8192] ----
__global__ __launch_bounds__(512) void k_gnorm(const float* __restrict__ gproj, float* __restrict__ outg) {
  const int n = blockIdx.x;
  const int t = threadIdx.x;
  float v = gproj[n * F_ + t];
  float s = v * v;
  const int lane = t & 63, wv = t >> 6;
  #pragma unroll
  for (int off = 32; off >= 1; off >>= 1) s += __shfl_down(s, off);
  __shared__ float red[8];
  __shared__ float rtot;
  if (lane == 0) red[wv] = s;
  __syncthreads();
  if (t == 0) {
    float a = 0.f;
    #pragma unroll
    for (int i = 0; i < 8; ++i) a += red[i];
    rtot = 1.0f / fmaxf(sqrtf(a), 1e-12f);
  }
  __syncthreads();
  outg[n * F_ + t] = v * rtot;
}

extern "C" void kernel_launch(void* const* d_in, const int* in_sizes, int n_in,
                              void* d_out, int out_size, void* d_ws, size_t ws_size,
                              hipStream_t stream) {
  const float* x  = (const float*)d_in[0];
  const float* pw = (const float*)d_in[1];
  const float* pb = (const float*)d_in[2];
  const float* pv = (const float*)d_in[3];
  float* out = (float*)d_out;

  char* ws = (char*)d_ws;
  float* sumsq = (float*)ws;                                   // 64 KB
  float* gbuf  = (float*)(ws + 65536);                         // 128 KB
  float* gg    = (float*)(ws + 65536 + 131072);                // 128 KB
  float* gproj = (float*)(ws + 65536 + 2 * 131072);            // 32 KB
  u16*   wb    = (u16*)(ws + 65536 + 2 * 131072 + 32768);      // 2 MiB
  u16*   boxT  = (u16*)(ws + 4u * 1024u * 1024u);              // 64 MiB: [16384 rows][2048] bf16

  hipMemsetAsync(d_ws, 0, 65536 + 131072, stream);   // zero sumsq + gbuf

  k_sumsq<<<dim3(16, 32), dim3(256), 0, stream>>>(x, sumsq);
  k_wconv<<<dim3(1024), dim3(256), 0, stream>>>(pw, wb);
  k_box<<<dim3(16, 16, 8), dim3(256), 0, stream>>>(x, sumsq, pv, gbuf, boxT);
  k_gem_fin<<<dim3(128), dim3(256), 0, stream>>>(gbuf, pv, gg);
  k_gproj<<<dim3(512), dim3(256), 0, stream>>>(pw, pb, gg, gproj);
  k_gnorm<<<dim3(16), dim3(512), 0, stream>>>(gproj, out);
  k_gemm<<<dim3(256), dim3(512), 0, stream>>>(boxT, wb, pb, out + N_ * F_);
}

// Round 3
// 190.760 us; speedup vs baseline: 1.3890x; 1.3890x over previous
//
#include <hip/hip_runtime.h>
#include <hip/hip_bf16.h>

#define N_ 16
#define D_ 2048
#define H_ 32
#define W_ 32
#define HW_ 1024
#define F_ 512

typedef unsigned short u16;
typedef unsigned int u32;
typedef __attribute__((ext_vector_type(8))) short bf16x8;
typedef __attribute__((ext_vector_type(4))) float f32x4;

__device__ __forceinline__ u16 f2bf(float f) {
  union { float fv; u32 u; } c; c.fv = f;
  u32 u = c.u;
  u32 r = (u + 0x7fffu + ((u >> 16) & 1u)) >> 16;   // RNE
  return (u16)r;
}

#define GLD_LDS16(gp, lp) __builtin_amdgcn_global_load_lds( \
    (const __attribute__((address_space(1))) void*)(gp), \
    (__attribute__((address_space(3))) void*)(lp), 16, 0, 0)

// ---- K1: sum of squares over channel dim -> sumsq[n][hw] (atomic partials) ----
__global__ __launch_bounds__(256) void k_sumsq(const float* __restrict__ x, float* __restrict__ sumsq) {
  const int n = blockIdx.x;        // 16
  const int dc = blockIdx.y;       // 32 chunks x 64 d
  const int t = threadIdx.x;
  const float* xp = x + ((size_t)n * D_ + (size_t)dc * 64) * HW_;
  float s0 = 0.f, s1 = 0.f, s2 = 0.f, s3 = 0.f;
  for (int d = 0; d < 64; ++d) {
    const float* row = xp + (size_t)d * HW_;
    float v0 = row[t], v1 = row[t + 256], v2 = row[t + 512], v3 = row[t + 768];
    s0 += v0 * v0; s1 += v1 * v1; s2 += v2 * v2; s3 += v3 * v3;
  }
  atomicAdd(&sumsq[n * HW_ + t      ], s0);
  atomicAdd(&sumsq[n * HW_ + t + 256], s1);
  atomicAdd(&sumsq[n * HW_ + t + 512], s2);
  atomicAdd(&sumsq[n * HW_ + t + 768], s3);
}

// ---- K2: register-resident separable 3x3 box + GeM partials ----
// grid (n=16, ht=8, dc=32); block 256. thread: w = t&31 spatial col, g = t>>5 d-subgroup.
// Each thread handles 8 d's (d = d0 + g*8 + j), 6 h rows in registers.
__global__ __launch_bounds__(256) void k_box2(const float* __restrict__ x,
    const float* __restrict__ sumsq, const float* __restrict__ pvec,
    float* __restrict__ gbuf, u16* __restrict__ boxT) {
  const int n = blockIdx.x, ht = blockIdx.y, dc = blockIdx.z;
  const int h0 = ht * 4, d0 = dc * 64;
  const int t = threadIdx.x;
  const int w = t & 31, g = t >> 5;
  const float p = pvec[0];
  const bool p3 = (p == 3.0f);

  __shared__ __align__(16) u16 sbox[128 * 68];   // [hw 128][d 64 pad->68]

  // per-(h,w) inverse norms for the 6-row window
  float rn[6];
  #pragma unroll
  for (int jj = 0; jj < 6; ++jj) {
    int hp = h0 - 1 + jj;
    float r = 0.f;
    if (hp >= 0 && hp < H_) r = 1.0f / fmaxf(sqrtf(sumsq[n * HW_ + hp * W_ + w]), 1e-12f);
    rn[jj] = r;
  }

  float s[8];
  #pragma unroll
  for (int j = 0; j < 8; ++j) s[j] = 0.f;

  #pragma unroll 2
  for (int j = 0; j < 8; ++j) {
    const int d = d0 + g * 8 + j;
    const float* col = x + ((size_t)(n * D_ + d)) * HW_ + w;
    float v[6];
    #pragma unroll
    for (int jj = 0; jj < 6; ++jj) {
      int hp = h0 - 1 + jj;
      float xv = (hp >= 0 && hp < H_) ? col[hp * W_] : 0.f;
      v[jj] = xv * rn[jj];
    }
    // GeM partial over the 4 owned rows
    #pragma unroll
    for (int jj = 1; jj <= 4; ++jj) {
      float cv = fmaxf(v[jj], 1e-6f);
      s[j] += p3 ? cv * cv * cv : __powf(cv, p);
    }
    // horizontal 3-tap via shuffles within 32-lane w-groups
    float hs[6];
    #pragma unroll
    for (int jj = 0; jj < 6; ++jj) {
      float l = __shfl_up(v[jj], 1, 32);
      float r = __shfl_down(v[jj], 1, 32);
      if (w == 0) l = 0.f;
      if (w == 31) r = 0.f;
      hs[jj] = l + v[jj] + r;
    }
    // vertical 3-tap + LDS transpose-stage (bf16)
    #pragma unroll
    for (int k = 0; k < 4; ++k) {
      float b = hs[k] + hs[k + 1] + hs[k + 2];
      sbox[(k * 32 + w) * 68 + g * 8 + j] = f2bf(b);
    }
  }
  __syncthreads();

  // coalesced store: thread -> 64 B (32 bf16) of one hw row
  {
    const int r = t >> 1, half = t & 1;
    const u16* srcp = sbox + r * 68 + half * 32;
    uint2 a[8];
    #pragma unroll
    for (int q = 0; q < 8; ++q) a[q] = *(const uint2*)(srcp + q * 4);
    u16* dst = boxT + ((size_t)(n * HW_ + h0 * W_ + r)) * D_ + d0 + half * 32;
    #pragma unroll
    for (int q = 0; q < 4; ++q) {
      uint4 b;
      b.x = a[2 * q].x; b.y = a[2 * q].y; b.z = a[2 * q + 1].x; b.w = a[2 * q + 1].y;
      ((uint4*)dst)[q] = b;
    }
  }

  // GeM reduce over the 32 w-lanes, one atomic per d per 32-group
  #pragma unroll
  for (int j = 0; j < 8; ++j) {
    float v = s[j];
    v += __shfl_xor(v, 16, 32);
    v += __shfl_xor(v, 8, 32);
    v += __shfl_xor(v, 4, 32);
    v += __shfl_xor(v, 2, 32);
    v += __shfl_xor(v, 1, 32);
    if (w == 0) atomicAdd(&gbuf[n * D_ + d0 + g * 8 + j], v);
  }
}

// ---- K3: proj_w fp32 -> bf16 ----
__global__ __launch_bounds__(256) void k_wconv(const float* __restrict__ w, u16* __restrict__ wb) {
  int i = blockIdx.x * 256 + threadIdx.x;      // 262144 threads, 4 elems each
  float4 v = ((const float4*)w)[i];
  u16 r[4] = { f2bf(v.x), f2bf(v.y), f2bf(v.z), f2bf(v.w) };
  *(uint2*)(wb + (size_t)i * 4) = *(const uint2*)r;
}

// ---- K4: GEMM [64 hw] x [512 f] x [K 2048] + bias + l2norm over f + transposed store ----
__global__ __launch_bounds__(512) void k_gemm(const u16* __restrict__ boxT,
    const u16* __restrict__ wb, const float* __restrict__ bias,
    float* __restrict__ outL) {
  const int n  = blockIdx.x >> 4;
  const int mt = blockIdx.x & 15;
  const int m0 = n * HW_ + mt * 64;
  const int hw0 = mt * 64;
  const int t = threadIdx.x;
  const int lane = t & 63, wv = t >> 6;

  __shared__ __align__(16) u16 smem[64 * 32 + 512 * 32];  // sA | sB (linear, for global_load_lds)
  u16* sA = smem;
  u16* sB = smem + 64 * 32;
  __shared__ float s_sq[8][64];
  __shared__ float s_rn[64];

  f32x4 acc[4][4];
  #pragma unroll
  for (int a = 0; a < 4; ++a)
    #pragma unroll
    for (int b = 0; b < 4; ++b) acc[a][b] = (f32x4){0.f, 0.f, 0.f, 0.f};

  const int lrow4 = lane >> 2;        // 0..15
  const int lk8   = (lane & 3) * 8;   // 0,8,16,24

  for (int kt = 0; kt < D_ / 32; ++kt) {
    const int k0 = kt * 32;
    #pragma unroll
    for (int q = 0; q < 4; ++q) {        // B tile: 512x32 bf16 = 32 chunks of 1KB
      int c = wv * 4 + q;
      int frow = c * 16 + lrow4;
      GLD_LDS16(wb + (size_t)frow * D_ + k0 + lk8, (char*)sB + (size_t)c * 1024);
    }
    if (wv < 4) {                        // A tile: 64x32 bf16 = 4 chunks
      int r = wv * 16 + lrow4;
      GLD_LDS16(boxT + (size_t)(m0 + r) * D_ + k0 + lk8, (char*)sA + (size_t)wv * 1024);
    }
    __syncthreads();
    bf16x8 af[4], bfv[4];
    #pragma unroll
    for (int mf = 0; mf < 4; ++mf)
      af[mf] = *(const bf16x8*)(sA + (mf * 16 + (lane & 15)) * 32 + (lane >> 4) * 8);
    #pragma unroll
    for (int nf = 0; nf < 4; ++nf)
      bfv[nf] = *(const bf16x8*)(sB + (wv * 64 + nf * 16 + (lane & 15)) * 32 + (lane >> 4) * 8);
    #pragma unroll
    for (int mf = 0; mf < 4; ++mf)
      #pragma unroll
      for (int nf = 0; nf < 4; ++nf)
        acc[mf][nf] = __builtin_amdgcn_mfma_f32_16x16x32_bf16(af[mf], bfv[nf], acc[mf][nf], 0, 0, 0);
    __syncthreads();
  }

  // epilogue: bias, per-row (hw) l2 norm over all 512 f, transposed store
  float badd[4];
  #pragma unroll
  for (int nf = 0; nf < 4; ++nf) badd[nf] = bias[wv * 64 + nf * 16 + (lane & 15)];
  #pragma unroll
  for (int mf = 0; mf < 4; ++mf)
    #pragma unroll
    for (int nf = 0; nf < 4; ++nf)
      #pragma unroll
      for (int j = 0; j < 4; ++j) acc[mf][nf][j] += badd[nf];

  #pragma unroll
  for (int mf = 0; mf < 4; ++mf)
    #pragma unroll
    for (int j = 0; j < 4; ++j) {
      float s = 0.f;
      #pragma unroll
      for (int nf = 0; nf < 4; ++nf) { float v = acc[mf][nf][j]; s += v * v; }
      s += __shfl_xor(s, 1); s += __shfl_xor(s, 2); s += __shfl_xor(s, 4); s += __shfl_xor(s, 8);
      if ((lane & 15) == 0) s_sq[wv][mf * 16 + (lane >> 4) * 4 + j] = s;
    }
  __syncthreads();
  if (t < 64) {
    float s = 0.f;
    #pragma unroll
    for (int w8 = 0; w8 < 8; ++w8) s += s_sq[w8][t];
    s_rn[t] = 1.0f / fmaxf(sqrtf(s), 1e-12f);
  }
  __syncthreads();

  float* ct = (float*)smem;   // reuse staging LDS: [128 f-rows][68] fp32
  for (int nf = 0; nf < 4; ++nf) {
    const int fi = wv * 16 + (lane & 15);
    #pragma unroll
    for (int mf = 0; mf < 4; ++mf)
      #pragma unroll
      for (int j = 0; j < 4; ++j) {
        int m = mf * 16 + (lane >> 4) * 4 + j;
        ct[fi * 68 + m] = acc[mf][nf][j] * s_rn[m];
      }
    __syncthreads();
    {
      int fr = t >> 2, mq = t & 3;
      int f = (fr >> 4) * 64 + nf * 16 + (fr & 15);
      float* dst = outL + ((size_t)(n * F_ + f)) * HW_ + hw0 + mq * 16;
      const float* srcp = ct + fr * 68 + mq * 16;
      float4 a0 = *(const float4*)(srcp);
      float4 a1 = *(const float4*)(srcp + 4);
      float4 a2 = *(const float4*)(srcp + 8);
      float4 a3 = *(const float4*)(srcp + 12);
      *(float4*)(dst) = a0; *(float4*)(dst + 4) = a1;
      *(float4*)(dst + 8) = a2; *(float4*)(dst + 12) = a3;
    }
    __syncthreads();
  }
}

// ---- K5: GeM finalize: gg = (gbuf/1024)^(1/p) ----
__global__ __launch_bounds__(256) void k_gem_fin(const float* __restrict__ gbuf,
    const float* __restrict__ pvec, float* __restrict__ gg) {
  int i = blockIdx.x * 256 + threadIdx.x;   // 32768
  float p = pvec[0];
  float m = gbuf[i] * (1.0f / 1024.0f);
  gg[i] = (p == 3.0f) ? cbrtf(m) : powf(m, 1.0f / p);
}

// ---- K6: gproj[n][f] = dot(gg[n], W[f]) + b[f] ----
__global__ __launch_bounds__(256) void k_gproj(const float* __restrict__ w,
    const float* __restrict__ bias, const float* __restrict__ gg,
    float* __restrict__ gproj) {
  const int f = blockIdx.x;     // 512
  const int t = threadIdx.x;
  float wreg[8];
  #pragma unroll
  for (int j = 0; j < 8; ++j) wreg[j] = w[(size_t)f * D_ + t + j * 256];
  __shared__ float red[4];
  const int lane = t & 63, wv = t >> 6;
  for (int n = 0; n < N_; ++n) {
    float s = 0.f;
    #pragma unroll
    for (int j = 0; j < 8; ++j) s += wreg[j] * gg[n * D_ + t + j * 256];
    #pragma unroll
    for (int off = 32; off >= 1; off >>= 1) s += __shfl_down(s, off);
    if (lane == 0) red[wv] = s;
    __syncthreads();
    if (t == 0) gproj[n * F_ + f] = red[0] + red[1] + red[2] + red[3] + bias[f];
    __syncthreads();
  }
}

// ---- K7: l2norm g rows -> d_out[0:8192] ----
__global__ __launch_bounds__(512) void k_gnorm(const float* __restrict__ gproj, float* __restrict__ outg) {
  const int n = blockIdx.x;
  const int t = threadIdx.x;
  float v = gproj[n * F_ + t];
  float s = v * v;
  const int lane = t & 63, wv = t >> 6;
  #pragma unroll
  for (int off = 32; off >= 1; off >>= 1) s += __shfl_down(s, off);
  __shared__ float red[8];
  __shared__ float rtot;
  if (lane == 0) red[wv] = s;
  __syncthreads();
  if (t == 0) {
    float a = 0.f;
    #pragma unroll
    for (int i = 0; i < 8; ++i) a += red[i];
    rtot = 1.0f / fmaxf(sqrtf(a), 1e-12f);
  }
  __syncthreads();
  outg[n * F_ + t] = v * rtot;
}

extern "C" void kernel_launch(void* const* d_in, const int* in_sizes, int n_in,
                              void* d_out, int out_size, void* d_ws, size_t ws_size,
                              hipStream_t stream) {
  const float* x  = (const float*)d_in[0];
  const float* pw = (const float*)d_in[1];
  const float* pb = (const float*)d_in[2];
  const float* pv = (const float*)d_in[3];
  float* out = (float*)d_out;

  char* ws = (char*)d_ws;
  float* sumsq = (float*)ws;                                   // 64 KB
  float* gbuf  = (float*)(ws + 65536);                         // 128 KB
  float* gg    = (float*)(ws + 65536 + 131072);                // 128 KB
  float* gproj = (float*)(ws + 65536 + 2 * 131072);            // 32 KB
  u16*   wb    = (u16*)(ws + 65536 + 2 * 131072 + 32768);      // 2 MiB
  u16*   boxT  = (u16*)(ws + 4u * 1024u * 1024u);              // 64 MiB: [16384 rows][2048] bf16

  hipMemsetAsync(d_ws, 0, 65536 + 131072, stream);   // zero sumsq + gbuf

  k_sumsq<<<dim3(16, 32), dim3(256), 0, stream>>>(x, sumsq);
  k_wconv<<<dim3(1024), dim3(256), 0, stream>>>(pw, wb);
  k_box2<<<dim3(16, 8, 32), dim3(256), 0, stream>>>(x, sumsq, pv, gbuf, boxT);
  k_gem_fin<<<dim3(128), dim3(256), 0, stream>>>(gbuf, pv, gg);
  k_gproj<<<dim3(512), dim3(256), 0, stream>>>(pw, pb, gg, gproj);
  k_gnorm<<<dim3(16), dim3(512), 0, stream>>>(gproj, out);
  k_gemm<<<dim3(256), dim3(512), 0, stream>>>(boxT, wb, pb, out + N_ * F_);
}

// Round 4
// 185.349 us; speedup vs baseline: 1.4296x; 1.0292x over previous
//
#include <hip/hip_runtime.h>
#include <hip/hip_bf16.h>

#define N_ 16
#define D_ 2048
#define H_ 32
#define W_ 32
#define HW_ 1024
#define F_ 512

typedef unsigned short u16;
typedef unsigned int u32;
typedef __attribute__((ext_vector_type(8))) short bf16x8;
typedef __attribute__((ext_vector_type(4))) float f32x4;

__device__ __forceinline__ u16 f2bf(float f) {
  union { float fv; u32 u; } c; c.fv = f;
  u32 u = c.u;
  u32 r = (u + 0x7fffu + ((u >> 16) & 1u)) >> 16;   // RNE
  return (u16)r;
}

#define GLD_LDS16(gp, lp) __builtin_amdgcn_global_load_lds( \
    (const __attribute__((address_space(1))) void*)(gp), \
    (__attribute__((address_space(3))) void*)(lp), 16, 0, 0)

// ---- K1: sum of squares over channel dim -> sumsq[n][hw] (atomic partials) ----
__global__ __launch_bounds__(256) void k_sumsq(const float* __restrict__ x, float* __restrict__ sumsq) {
  const int n = blockIdx.x;        // 16
  const int dc = blockIdx.y;       // 32 chunks x 64 d
  const int t = threadIdx.x;
  const float* xp = x + ((size_t)n * D_ + (size_t)dc * 64) * HW_;
  float s0 = 0.f, s1 = 0.f, s2 = 0.f, s3 = 0.f;
  for (int d = 0; d < 64; ++d) {
    const float* row = xp + (size_t)d * HW_;
    float v0 = row[t], v1 = row[t + 256], v2 = row[t + 512], v3 = row[t + 768];
    s0 += v0 * v0; s1 += v1 * v1; s2 += v2 * v2; s3 += v3 * v3;
  }
  atomicAdd(&sumsq[n * HW_ + t      ], s0);
  atomicAdd(&sumsq[n * HW_ + t + 256], s1);
  atomicAdd(&sumsq[n * HW_ + t + 512], s2);
  atomicAdd(&sumsq[n * HW_ + t + 768], s3);
}

// ---- K2: register-resident separable 3x3 box + GeM partials ----
__global__ __launch_bounds__(256) void k_box2(const float* __restrict__ x,
    const float* __restrict__ sumsq, const float* __restrict__ pvec,
    float* __restrict__ gbuf, u16* __restrict__ boxT) {
  const int n = blockIdx.x, ht = blockIdx.y, dc = blockIdx.z;
  const int h0 = ht * 4, d0 = dc * 64;
  const int t = threadIdx.x;
  const int w = t & 31, g = t >> 5;
  const float p = pvec[0];
  const bool p3 = (p == 3.0f);

  __shared__ __align__(16) u16 sbox[128 * 68];   // [hw 128][d 64 pad->68]

  float rn[6];
  #pragma unroll
  for (int jj = 0; jj < 6; ++jj) {
    int hp = h0 - 1 + jj;
    float r = 0.f;
    if (hp >= 0 && hp < H_) r = 1.0f / fmaxf(sqrtf(sumsq[n * HW_ + hp * W_ + w]), 1e-12f);
    rn[jj] = r;
  }

  float s[8];
  #pragma unroll
  for (int j = 0; j < 8; ++j) s[j] = 0.f;

  #pragma unroll 2
  for (int j = 0; j < 8; ++j) {
    const int d = d0 + g * 8 + j;
    const float* col = x + ((size_t)(n * D_ + d)) * HW_ + w;
    float v[6];
    #pragma unroll
    for (int jj = 0; jj < 6; ++jj) {
      int hp = h0 - 1 + jj;
      float xv = (hp >= 0 && hp < H_) ? col[hp * W_] : 0.f;
      v[jj] = xv * rn[jj];
    }
    #pragma unroll
    for (int jj = 1; jj <= 4; ++jj) {
      float cv = fmaxf(v[jj], 1e-6f);
      s[j] += p3 ? cv * cv * cv : __powf(cv, p);
    }
    float hs[6];
    #pragma unroll
    for (int jj = 0; jj < 6; ++jj) {
      float l = __shfl_up(v[jj], 1, 32);
      float r = __shfl_down(v[jj], 1, 32);
      if (w == 0) l = 0.f;
      if (w == 31) r = 0.f;
      hs[jj] = l + v[jj] + r;
    }
    #pragma unroll
    for (int k = 0; k < 4; ++k) {
      float b = hs[k] + hs[k + 1] + hs[k + 2];
      sbox[(k * 32 + w) * 68 + g * 8 + j] = f2bf(b);
    }
  }
  __syncthreads();

  {
    const int r = t >> 1, half = t & 1;
    const u16* srcp = sbox + r * 68 + half * 32;
    uint2 a[8];
    #pragma unroll
    for (int q = 0; q < 8; ++q) a[q] = *(const uint2*)(srcp + q * 4);
    u16* dst = boxT + ((size_t)(n * HW_ + h0 * W_ + r)) * D_ + d0 + half * 32;
    #pragma unroll
    for (int q = 0; q < 4; ++q) {
      uint4 b;
      b.x = a[2 * q].x; b.y = a[2 * q].y; b.z = a[2 * q + 1].x; b.w = a[2 * q + 1].y;
      ((uint4*)dst)[q] = b;
    }
  }

  #pragma unroll
  for (int j = 0; j < 8; ++j) {
    float v = s[j];
    v += __shfl_xor(v, 16, 32);
    v += __shfl_xor(v, 8, 32);
    v += __shfl_xor(v, 4, 32);
    v += __shfl_xor(v, 2, 32);
    v += __shfl_xor(v, 1, 32);
    if (w == 0) atomicAdd(&gbuf[n * D_ + d0 + g * 8 + j], v);
  }
}

// ---- K3: proj_w fp32 -> bf16 ----
__global__ __launch_bounds__(256) void k_wconv(const float* __restrict__ w, u16* __restrict__ wb) {
  int i = blockIdx.x * 256 + threadIdx.x;
  float4 v = ((const float4*)w)[i];
  u16 r[4] = { f2bf(v.x), f2bf(v.y), f2bf(v.z), f2bf(v.w) };
  *(uint2*)(wb + (size_t)i * 4) = *(const uint2*)r;
}

// ---- K4: GEMM [64 hw] x [512 f] x [K 2048], 2-phase prefetch, swizzled LDS ----
// LDS layout per buffer: sA 64x32 bf16 (4KB) | sB 512x32 bf16 (32KB), rows 64B.
// Swizzle: 16B slot' = slot ^ ((row>>1)&3), applied on the GLOBAL source at stage
// time (LDS dest stays linear, rule 21) and on the ds_read address.
__global__ __launch_bounds__(512) void k_gemm(const u16* __restrict__ boxT,
    const u16* __restrict__ wb, const float* __restrict__ bias,
    float* __restrict__ outL) {
  const int n  = blockIdx.x >> 4;
  const int mt = blockIdx.x & 15;
  const int m0 = n * HW_ + mt * 64;
  const int hw0 = mt * 64;
  const int t = threadIdx.x;
  const int lane = t & 63, wv = t >> 6;

  __shared__ __align__(16) u16 smem[2 * 18432];  // 2 x (sA 2048 + sB 16384) u16 = 72KB
  __shared__ float s_sq[8][64];
  __shared__ float s_rn[64];

  f32x4 acc[4][4];
  #pragma unroll
  for (int a = 0; a < 4; ++a)
    #pragma unroll
    for (int b = 0; b < 4; ++b) acc[a][b] = (f32x4){0.f, 0.f, 0.f, 0.f};

  // staging: lane l stages 16B of row (l>>2) at LDS slot (l&3); global k-slot is
  // pre-swizzled so LDS(row, s) holds global slot s ^ ((row>>1)&3).
  const int kswz = ((lane & 3) ^ ((lane >> 3) & 3)) * 8;     // elements
  const u16* bsrc = wb + (size_t)(wv * 64 + (lane >> 2)) * D_ + kswz;   // chunk base rows wv*64.. (4 chunks of 16 rows)
  const u16* asrc = boxT + (size_t)(m0 + wv * 16 + (lane >> 2)) * D_ + kswz;  // wv<4 only

  const int r15 = lane & 15;
  const int slot = (((lane >> 4) ^ ((r15 >> 1) & 3))) * 8;   // read-side swizzled slot (elements)

  for (int kt = 0; kt < 65; ++kt) {
    // stage tile kt into buf kt&1 (except last iteration)
    if (kt < 64) {
      const int k0 = kt * 32;
      char* sAb = (char*)(smem + (kt & 1) * 18432);
      char* sBb = sAb + 4096;
      #pragma unroll
      for (int q = 0; q < 4; ++q)
        GLD_LDS16(bsrc + (size_t)q * 16 * D_ + k0, sBb + (wv * 4 + q) * 1024);
      if (wv < 4)
        GLD_LDS16(asrc + k0, sAb + wv * 1024);
    }
    // compute tile kt-1 from buf (kt-1)&1 (skip first iteration)
    if (kt > 0) {
      const u16* sA = smem + ((kt - 1) & 1) * 18432;
      const u16* sB = sA + 2048;
      bf16x8 af[4], bfv[4];
      #pragma unroll
      for (int mf = 0; mf < 4; ++mf)
        af[mf] = *(const bf16x8*)(sA + (mf * 16 + r15) * 32 + slot);
      #pragma unroll
      for (int nf = 0; nf < 4; ++nf)
        bfv[nf] = *(const bf16x8*)(sB + (wv * 64 + nf * 16 + r15) * 32 + slot);
      #pragma unroll
      for (int mf = 0; mf < 4; ++mf)
        #pragma unroll
        for (int nf = 0; nf < 4; ++nf)
          acc[mf][nf] = __builtin_amdgcn_mfma_f32_16x16x32_bf16(af[mf], bfv[nf], acc[mf][nf], 0, 0, 0);
    }
    __syncthreads();   // drains vmcnt (staged tile kt ready) + all reads of old buf done
  }

  // epilogue: bias, per-row (hw) l2 norm over all 512 f, transposed store
  float badd[4];
  #pragma unroll
  for (int nf = 0; nf < 4; ++nf) badd[nf] = bias[wv * 64 + nf * 16 + r15];
  #pragma unroll
  for (int mf = 0; mf < 4; ++mf)
    #pragma unroll
    for (int nf = 0; nf < 4; ++nf)
      #pragma unroll
      for (int j = 0; j < 4; ++j) acc[mf][nf][j] += badd[nf];

  #pragma unroll
  for (int mf = 0; mf < 4; ++mf)
    #pragma unroll
    for (int j = 0; j < 4; ++j) {
      float s = 0.f;
      #pragma unroll
      for (int nf = 0; nf < 4; ++nf) { float v = acc[mf][nf][j]; s += v * v; }
      s += __shfl_xor(s, 1); s += __shfl_xor(s, 2); s += __shfl_xor(s, 4); s += __shfl_xor(s, 8);
      if ((lane & 15) == 0) s_sq[wv][mf * 16 + (lane >> 4) * 4 + j] = s;
    }
  __syncthreads();
  if (t < 64) {
    float s = 0.f;
    #pragma unroll
    for (int w8 = 0; w8 < 8; ++w8) s += s_sq[w8][t];
    s_rn[t] = 1.0f / fmaxf(sqrtf(s), 1e-12f);
  }
  __syncthreads();

  float* ct = (float*)smem;   // reuse staging LDS: [128 f-rows][68] fp32
  for (int nf = 0; nf < 4; ++nf) {
    const int fi = wv * 16 + r15;
    #pragma unroll
    for (int mf = 0; mf < 4; ++mf)
      #pragma unroll
      for (int j = 0; j < 4; ++j) {
        int m = mf * 16 + (lane >> 4) * 4 + j;
        ct[fi * 68 + m] = acc[mf][nf][j] * s_rn[m];
      }
    __syncthreads();
    {
      int fr = t >> 2, mq = t & 3;
      int f = (fr >> 4) * 64 + nf * 16 + (fr & 15);
      float* dst = outL + ((size_t)(n * F_ + f)) * HW_ + hw0 + mq * 16;
      const float* srcp = ct + fr * 68 + mq * 16;
      float4 a0 = *(const float4*)(srcp);
      float4 a1 = *(const float4*)(srcp + 4);
      float4 a2 = *(const float4*)(srcp + 8);
      float4 a3 = *(const float4*)(srcp + 12);
      *(float4*)(dst) = a0; *(float4*)(dst + 4) = a1;
      *(float4*)(dst + 8) = a2; *(float4*)(dst + 12) = a3;
    }
    __syncthreads();
  }
}

// ---- K5: GeM finalize: gg = (gbuf/1024)^(1/p) ----
__global__ __launch_bounds__(256) void k_gem_fin(const float* __restrict__ gbuf,
    const float* __restrict__ pvec, float* __restrict__ gg) {
  int i = blockIdx.x * 256 + threadIdx.x;
  float p = pvec[0];
  float m = gbuf[i] * (1.0f / 1024.0f);
  gg[i] = (p == 3.0f) ? cbrtf(m) : powf(m, 1.0f / p);
}

// ---- K6: gproj[n][f] = dot(gg[n], W[f]) + b[f] ----
__global__ __launch_bounds__(256) void k_gproj(const float* __restrict__ w,
    const float* __restrict__ bias, const float* __restrict__ gg,
    float* __restrict__ gproj) {
  const int f = blockIdx.x;
  const int t = threadIdx.x;
  float wreg[8];
  #pragma unroll
  for (int j = 0; j < 8; ++j) wreg[j] = w[(size_t)f * D_ + t + j * 256];
  __shared__ float red[4];
  const int lane = t & 63, wv = t >> 6;
  for (int n = 0; n < N_; ++n) {
    float s = 0.f;
    #pragma unroll
    for (int j = 0; j < 8; ++j) s += wreg[j] * gg[n * D_ + t + j * 256];
    #pragma unroll
    for (int off = 32; off >= 1; off >>= 1) s += __shfl_down(s, off);
    if (lane == 0) red[wv] = s;
    __syncthreads();
    if (t == 0) gproj[n * F_ + f] = red[0] + red[1] + red[2] + red[3] + bias[f];
    __syncthreads();
  }
}

// ---- K7: l2norm g rows -> d_out[0:8192] ----
__global__ __launch_bounds__(512) void k_gnorm(const float* __restrict__ gproj, float* __restrict__ outg) {
  const int n = blockIdx.x;
  const int t = threadIdx.x;
  float v = gproj[n * F_ + t];
  float s = v * v;
  const int lane = t & 63, wv = t >> 6;
  #pragma unroll
  for (int off = 32; off >= 1; off >>= 1) s += __shfl_down(s, off);
  __shared__ float red[8];
  __shared__ float rtot;
  if (lane == 0) red[wv] = s;
  __syncthreads();
  if (t == 0) {
    float a = 0.f;
    #pragma unroll
    for (int i = 0; i < 8; ++i) a += red[i];
    rtot = 1.0f / fmaxf(sqrtf(a), 1e-12f);
  }
  __syncthreads();
  outg[n * F_ + t] = v * rtot;
}

extern "C" void kernel_launch(void* const* d_in, const int* in_sizes, int n_in,
                              void* d_out, int out_size, void* d_ws, size_t ws_size,
                              hipStream_t stream) {
  const float* x  = (const float*)d_in[0];
  const float* pw = (const float*)d_in[1];
  const float* pb = (const float*)d_in[2];
  const float* pv = (const float*)d_in[3];
  float* out = (float*)d_out;

  char* ws = (char*)d_ws;
  float* sumsq = (float*)ws;                                   // 64 KB
  float* gbuf  = (float*)(ws + 65536);                         // 128 KB
  float* gg    = (float*)(ws + 65536 + 131072);                // 128 KB
  float* gproj = (float*)(ws + 65536 + 2 * 131072);            // 32 KB
  u16*   wb    = (u16*)(ws + 65536 + 2 * 131072 + 32768);      // 2 MiB
  u16*   boxT  = (u16*)(ws + 4u * 1024u * 1024u);              // 64 MiB: [16384 rows][2048] bf16

  hipMemsetAsync(d_ws, 0, 65536 + 131072, stream);   // zero sumsq + gbuf

  k_sumsq<<<dim3(16, 32), dim3(256), 0, stream>>>(x, sumsq);
  k_wconv<<<dim3(1024), dim3(256), 0, stream>>>(pw, wb);
  k_box2<<<dim3(16, 8, 32), dim3(256), 0, stream>>>(x, sumsq, pv, gbuf, boxT);
  k_gem_fin<<<dim3(128), dim3(256), 0, stream>>>(gbuf, pv, gg);
  k_gproj<<<dim3(512), dim3(256), 0, stream>>>(pw, pb, gg, gproj);
  k_gnorm<<<dim3(16), dim3(512), 0, stream>>>(gproj, out);
  k_gemm<<<dim3(256), dim3(512), 0, stream>>>(boxT, wb, pb, out + N_ * F_);
}

// Round 5
// 168.614 us; speedup vs baseline: 1.5715x; 1.0992x over previous
//
#include <hip/hip_runtime.h>
#include <hip/hip_bf16.h>

#define N_ 16
#define D_ 2048
#define H_ 32
#define W_ 32
#define HW_ 1024
#define F_ 512

typedef unsigned short u16;
typedef unsigned int u32;
typedef __attribute__((ext_vector_type(8))) short bf16x8;
typedef __attribute__((ext_vector_type(4))) float f32x4;

__device__ __forceinline__ u16 f2bf(float f) {
  union { float fv; u32 u; } c; c.fv = f;
  u32 u = c.u;
  u32 r = (u + 0x7fffu + ((u >> 16) & 1u)) >> 16;   // RNE
  return (u16)r;
}

#define GLD_LDS16(gp, lp) __builtin_amdgcn_global_load_lds( \
    (const __attribute__((address_space(1))) void*)(gp), \
    (__attribute__((address_space(3))) void*)(lp), 16, 0, 0)

// ---- K1: sum of squares over channel dim -> sumsq[n][hw] (atomic partials) ----
__global__ __launch_bounds__(256) void k_sumsq(const float* __restrict__ x, float* __restrict__ sumsq) {
  const int n = blockIdx.x;        // 16
  const int dc = blockIdx.y;       // 32 chunks x 64 d
  const int t = threadIdx.x;
  const float* xp = x + ((size_t)n * D_ + (size_t)dc * 64) * HW_;
  float s0 = 0.f, s1 = 0.f, s2 = 0.f, s3 = 0.f;
  for (int d = 0; d < 64; ++d) {
    const float* row = xp + (size_t)d * HW_;
    float v0 = row[t], v1 = row[t + 256], v2 = row[t + 512], v3 = row[t + 768];
    s0 += v0 * v0; s1 += v1 * v1; s2 += v2 * v2; s3 += v3 * v3;
  }
  atomicAdd(&sumsq[n * HW_ + t      ], s0);
  atomicAdd(&sumsq[n * HW_ + t + 256], s1);
  atomicAdd(&sumsq[n * HW_ + t + 512], s2);
  atomicAdd(&sumsq[n * HW_ + t + 768], s3);
}

// ---- K2: register-resident separable 3x3 box + GeM partials ----
__global__ __launch_bounds__(256) void k_box2(const float* __restrict__ x,
    const float* __restrict__ sumsq, const float* __restrict__ pvec,
    float* __restrict__ gbuf, u16* __restrict__ boxT) {
  const int n = blockIdx.x, ht = blockIdx.y, dc = blockIdx.z;
  const int h0 = ht * 4, d0 = dc * 64;
  const int t = threadIdx.x;
  const int w = t & 31, g = t >> 5;
  const float p = pvec[0];
  const bool p3 = (p == 3.0f);

  __shared__ __align__(16) u16 sbox[128 * 68];   // [hw 128][d 64 pad->68]

  float rn[6];
  #pragma unroll
  for (int jj = 0; jj < 6; ++jj) {
    int hp = h0 - 1 + jj;
    float r = 0.f;
    if (hp >= 0 && hp < H_) r = 1.0f / fmaxf(sqrtf(sumsq[n * HW_ + hp * W_ + w]), 1e-12f);
    rn[jj] = r;
  }

  float s[8];
  #pragma unroll
  for (int j = 0; j < 8; ++j) s[j] = 0.f;

  #pragma unroll 2
  for (int j = 0; j < 8; ++j) {
    const int d = d0 + g * 8 + j;
    const float* col = x + ((size_t)(n * D_ + d)) * HW_ + w;
    float v[6];
    #pragma unroll
    for (int jj = 0; jj < 6; ++jj) {
      int hp = h0 - 1 + jj;
      float xv = (hp >= 0 && hp < H_) ? col[hp * W_] : 0.f;
      v[jj] = xv * rn[jj];
    }
    #pragma unroll
    for (int jj = 1; jj <= 4; ++jj) {
      float cv = fmaxf(v[jj], 1e-6f);
      s[j] += p3 ? cv * cv * cv : __powf(cv, p);
    }
    float hs[6];
    #pragma unroll
    for (int jj = 0; jj < 6; ++jj) {
      float l = __shfl_up(v[jj], 1, 32);
      float r = __shfl_down(v[jj], 1, 32);
      if (w == 0) l = 0.f;
      if (w == 31) r = 0.f;
      hs[jj] = l + v[jj] + r;
    }
    #pragma unroll
    for (int k = 0; k < 4; ++k) {
      float b = hs[k] + hs[k + 1] + hs[k + 2];
      sbox[(k * 32 + w) * 68 + g * 8 + j] = f2bf(b);
    }
  }
  __syncthreads();

  {
    const int r = t >> 1, half = t & 1;
    const u16* srcp = sbox + r * 68 + half * 32;
    uint2 a[8];
    #pragma unroll
    for (int q = 0; q < 8; ++q) a[q] = *(const uint2*)(srcp + q * 4);
    u16* dst = boxT + ((size_t)(n * HW_ + h0 * W_ + r)) * D_ + d0 + half * 32;
    #pragma unroll
    for (int q = 0; q < 4; ++q) {
      uint4 b;
      b.x = a[2 * q].x; b.y = a[2 * q].y; b.z = a[2 * q + 1].x; b.w = a[2 * q + 1].y;
      ((uint4*)dst)[q] = b;
    }
  }

  #pragma unroll
  for (int j = 0; j < 8; ++j) {
    float v = s[j];
    v += __shfl_xor(v, 16, 32);
    v += __shfl_xor(v, 8, 32);
    v += __shfl_xor(v, 4, 32);
    v += __shfl_xor(v, 2, 32);
    v += __shfl_xor(v, 1, 32);
    if (w == 0) atomicAdd(&gbuf[n * D_ + d0 + g * 8 + j], v);
  }
}

// ---- K3: proj_w fp32 -> bf16 ----
__global__ __launch_bounds__(256) void k_wconv(const float* __restrict__ w, u16* __restrict__ wb) {
  int i = blockIdx.x * 256 + threadIdx.x;
  float4 v = ((const float4*)w)[i];
  u16 r[4] = { f2bf(v.x), f2bf(v.y), f2bf(v.z), f2bf(v.w) };
  *(uint2*)(wb + (size_t)i * 4) = *(const uint2*)r;
}

// ---- K4: GEMM [64 hw] x [512 f] x [K 2048], 4-buffer counted-vmcnt pipeline ----
// Per buffer: sA 64x32 bf16 (4KB) | sB 512x32 bf16 (32KB), rows 64B; 4 bufs = 144KB.
// Swizzle: 16B slot' = slot ^ ((row>>1)&3) applied on global source at stage time
// (LDS stays linear) and on the ds_read address. All waves issue 5 loads/tile
// (waves 0-3 duplicate the A chunk with identical bytes -> uniform vmcnt).
// Iter kt: stage(kt+2) -> vmcnt(10) [retire tile kt] -> s_barrier -> compute(kt).
// WAR safety: stage(kt+2) overwrites buf last read at compute(kt-2); every wave
// passed barrier(kt-1), which requires all waves' compute(kt-2) reads retired.
__global__ __launch_bounds__(512) void k_gemm(const u16* __restrict__ boxT,
    const u16* __restrict__ wb, const float* __restrict__ bias,
    float* __restrict__ outL) {
  const int n  = blockIdx.x >> 4;
  const int mt = blockIdx.x & 15;
  const int m0 = n * HW_ + mt * 64;
  const int hw0 = mt * 64;
  const int t = threadIdx.x;
  const int lane = t & 63, wv = t >> 6;

  __shared__ __align__(16) u16 smem[4 * 18432];  // 144 KB
  __shared__ float s_sq[8][64];
  __shared__ float s_rn[64];

  f32x4 acc[4][4];
  #pragma unroll
  for (int a = 0; a < 4; ++a)
    #pragma unroll
    for (int b = 0; b < 4; ++b) acc[a][b] = (f32x4){0.f, 0.f, 0.f, 0.f};

  // staging addresses: lane l stages 16B of row (l>>2) at LDS slot (l&3);
  // global k-slot pre-swizzled: LDS(row,s) holds global slot s ^ ((row>>1)&3).
  const int kswz = ((lane & 3) ^ ((lane >> 3) & 3)) * 8;     // elements
  const u16* bsrc = wb + (size_t)(wv * 64 + (lane >> 2)) * D_ + kswz;
  const u16* asrc = boxT + (size_t)(m0 + (wv & 3) * 16 + (lane >> 2)) * D_ + kswz;

  const int r15 = lane & 15;
  const int slot = ((lane >> 4) ^ ((r15 >> 1) & 3)) * 8;     // read-side swizzle (elems)

#define STAGE_TILE(KT) do {                                            \
    const int k0_ = (KT) * 32;                                         \
    char* sAb_ = (char*)(smem + ((KT) & 3) * 18432);                   \
    char* sBb_ = sAb_ + 4096;                                          \
    _Pragma("unroll")                                                  \
    for (int q = 0; q < 4; ++q)                                        \
      GLD_LDS16(bsrc + (size_t)q * 16 * D_ + k0_, sBb_ + (wv * 4 + q) * 1024); \
    GLD_LDS16(asrc + k0_, sAb_ + (wv & 3) * 1024);                     \
  } while (0)

  STAGE_TILE(0);
  STAGE_TILE(1);

  for (int kt = 0; kt < 64; ++kt) {
    if (kt + 2 < 64) STAGE_TILE(kt + 2);
    __builtin_amdgcn_sched_barrier(0);
    if (kt < 62) {
      asm volatile("s_waitcnt vmcnt(10)" ::: "memory");   // tile kt retired; kt+1,kt+2 in flight
    } else if (kt == 62) {
      asm volatile("s_waitcnt vmcnt(5)" ::: "memory");    // tile 62 retired; 63 in flight
    } else {
      asm volatile("s_waitcnt vmcnt(0)" ::: "memory");    // tile 63 retired
    }
    __builtin_amdgcn_sched_barrier(0);
    __builtin_amdgcn_s_barrier();                          // tile kt fully in LDS (all waves)
    __builtin_amdgcn_sched_barrier(0);

    const u16* sA = smem + (kt & 3) * 18432;
    const u16* sB = sA + 2048;
    bf16x8 af[4], bfv[4];
    #pragma unroll
    for (int mf = 0; mf < 4; ++mf)
      af[mf] = *(const bf16x8*)(sA + (mf * 16 + r15) * 32 + slot);
    #pragma unroll
    for (int nf = 0; nf < 4; ++nf)
      bfv[nf] = *(const bf16x8*)(sB + (wv * 64 + nf * 16 + r15) * 32 + slot);
    #pragma unroll
    for (int mf = 0; mf < 4; ++mf)
      #pragma unroll
      for (int nf = 0; nf < 4; ++nf)
        acc[mf][nf] = __builtin_amdgcn_mfma_f32_16x16x32_bf16(af[mf], bfv[nf], acc[mf][nf], 0, 0, 0);
  }
#undef STAGE_TILE

  // epilogue: bias, per-row (hw) l2 norm over all 512 f, transposed store
  float badd[4];
  #pragma unroll
  for (int nf = 0; nf < 4; ++nf) badd[nf] = bias[wv * 64 + nf * 16 + r15];
  #pragma unroll
  for (int mf = 0; mf < 4; ++mf)
    #pragma unroll
    for (int nf = 0; nf < 4; ++nf)
      #pragma unroll
      for (int j = 0; j < 4; ++j) acc[mf][nf][j] += badd[nf];

  #pragma unroll
  for (int mf = 0; mf < 4; ++mf)
    #pragma unroll
    for (int j = 0; j < 4; ++j) {
      float s = 0.f;
      #pragma unroll
      for (int nf = 0; nf < 4; ++nf) { float v = acc[mf][nf][j]; s += v * v; }
      s += __shfl_xor(s, 1); s += __shfl_xor(s, 2); s += __shfl_xor(s, 4); s += __shfl_xor(s, 8);
      if ((lane & 15) == 0) s_sq[wv][mf * 16 + (lane >> 4) * 4 + j] = s;
    }
  __syncthreads();
  if (t < 64) {
    float s = 0.f;
    #pragma unroll
    for (int w8 = 0; w8 < 8; ++w8) s += s_sq[w8][t];
    s_rn[t] = 1.0f / fmaxf(sqrtf(s), 1e-12f);
  }
  __syncthreads();

  float* ct = (float*)smem;   // reuse staging LDS: [128 f-rows][68] fp32
  for (int nf = 0; nf < 4; ++nf) {
    const int fi = wv * 16 + r15;
    #pragma unroll
    for (int mf = 0; mf < 4; ++mf)
      #pragma unroll
      for (int j = 0; j < 4; ++j) {
        int m = mf * 16 + (lane >> 4) * 4 + j;
        ct[fi * 68 + m] = acc[mf][nf][j] * s_rn[m];
      }
    __syncthreads();
    {
      int fr = t >> 2, mq = t & 3;
      int f = (fr >> 4) * 64 + nf * 16 + (fr & 15);
      float* dst = outL + ((size_t)(n * F_ + f)) * HW_ + hw0 + mq * 16;
      const float* srcp = ct + fr * 68 + mq * 16;
      float4 a0 = *(const float4*)(srcp);
      float4 a1 = *(const float4*)(srcp + 4);
      float4 a2 = *(const float4*)(srcp + 8);
      float4 a3 = *(const float4*)(srcp + 12);
      *(float4*)(dst) = a0; *(float4*)(dst + 4) = a1;
      *(float4*)(dst + 8) = a2; *(float4*)(dst + 12) = a3;
    }
    __syncthreads();
  }
}

// ---- K5: GeM finalize: gg = (gbuf/1024)^(1/p) ----
__global__ __launch_bounds__(256) void k_gem_fin(const float* __restrict__ gbuf,
    const float* __restrict__ pvec, float* __restrict__ gg) {
  int i = blockIdx.x * 256 + threadIdx.x;
  float p = pvec[0];
  float m = gbuf[i] * (1.0f / 1024.0f);
  gg[i] = (p == 3.0f) ? cbrtf(m) : powf(m, 1.0f / p);
}

// ---- K6: gproj[n][f] = dot(gg[n], W[f]) + b[f] ----
__global__ __launch_bounds__(256) void k_gproj(const float* __restrict__ w,
    const float* __restrict__ bias, const float* __restrict__ gg,
    float* __restrict__ gproj) {
  const int f = blockIdx.x;
  const int t = threadIdx.x;
  float wreg[8];
  #pragma unroll
  for (int j = 0; j < 8; ++j) wreg[j] = w[(size_t)f * D_ + t + j * 256];
  __shared__ float red[4];
  const int lane = t & 63, wv = t >> 6;
  for (int n = 0; n < N_; ++n) {
    float s = 0.f;
    #pragma unroll
    for (int j = 0; j < 8; ++j) s += wreg[j] * gg[n * D_ + t + j * 256];
    #pragma unroll
    for (int off = 32; off >= 1; off >>= 1) s += __shfl_down(s, off);
    if (lane == 0) red[wv] = s;
    __syncthreads();
    if (t == 0) gproj[n * F_ + f] = red[0] + red[1] + red[2] + red[3] + bias[f];
    __syncthreads();
  }
}

// ---- K7: l2norm g rows -> d_out[0:8192] ----
__global__ __launch_bounds__(512) void k_gnorm(const float* __restrict__ gproj, float* __restrict__ outg) {
  const int n = blockIdx.x;
  const int t = threadIdx.x;
  float v = gproj[n * F_ + t];
  float s = v * v;
  const int lane = t & 63, wv = t >> 6;
  #pragma unroll
  for (int off = 32; off >= 1; off >>= 1) s += __shfl_down(s, off);
  __shared__ float red[8];
  __shared__ float rtot;
  if (lane == 0) red[wv] = s;
  __syncthreads();
  if (t == 0) {
    float a = 0.f;
    #pragma unroll
    for (int i = 0; i < 8; ++i) a += red[i];
    rtot = 1.0f / fmaxf(sqrtf(a), 1e-12f);
  }
  __syncthreads();
  outg[n * F_ + t] = v * rtot;
}

extern "C" void kernel_launch(void* const* d_in, const int* in_sizes, int n_in,
                              void* d_out, int out_size, void* d_ws, size_t ws_size,
                              hipStream_t stream) {
  const float* x  = (const float*)d_in[0];
  const float* pw = (const float*)d_in[1];
  const float* pb = (const float*)d_in[2];
  const float* pv = (const float*)d_in[3];
  float* out = (float*)d_out;

  char* ws = (char*)d_ws;
  float* sumsq = (float*)ws;                                   // 64 KB
  float* gbuf  = (float*)(ws + 65536);                         // 128 KB
  float* gg    = (float*)(ws + 65536 + 131072);                // 128 KB
  float* gproj = (float*)(ws + 65536 + 2 * 131072);            // 32 KB
  u16*   wb    = (u16*)(ws + 65536 + 2 * 131072 + 32768);      // 2 MiB
  u16*   boxT  = (u16*)(ws + 4u * 1024u * 1024u);              // 64 MiB: [16384 rows][2048] bf16

  hipMemsetAsync(d_ws, 0, 65536 + 131072, stream);   // zero sumsq + gbuf

  k_sumsq<<<dim3(16, 32), dim3(256), 0, stream>>>(x, sumsq);
  k_wconv<<<dim3(1024), dim3(256), 0, stream>>>(pw, wb);
  k_box2<<<dim3(16, 8, 32), dim3(256), 0, stream>>>(x, sumsq, pv, gbuf, boxT);
  k_gem_fin<<<dim3(128), dim3(256), 0, stream>>>(gbuf, pv, gg);
  k_gproj<<<dim3(512), dim3(256), 0, stream>>>(pw, pb, gg, gproj);
  k_gnorm<<<dim3(16), dim3(512), 0, stream>>>(gproj, out);
  k_gemm<<<dim3(256), dim3(512), 0, stream>>>(boxT, wb, pb, out + N_ * F_);
}